// Round 16
// baseline (202.128 us; speedup 1.0000x reference)
//
#include <hip/hip_runtime.h>
#include <math.h>

#define SRLEN   640000
#define NFRAMES 2501
#define FPB     16
#define SPAN    (256*(FPB-1) + 1024)   // 4864
#define MROW    520                    // padded mag row in f32 (513 used, 514 padded)
#define MAXW    48                     // max mel filter width in bins (actual max ~28)

__device__ __forceinline__ int rev6(int x) { return (int)(__brev((unsigned)x) >> 26); }

// DPP lane-permute on the VALU pipe (not DS). ctrl: quad_perm / row mirrors.
// 0xB1 = quad_perm[1,0,3,2] (xor1)   0x4E = quad_perm[2,3,0,1] (xor2)
// 0x1B = quad_perm[3,2,1,0] (xor3)   0x140 = row_mirror (xor15)  0x141 = half_mirror (xor7)
#define DPPF(x, ctrl) __int_as_float(__builtin_amdgcn_update_dpp(0, __float_as_int(x), (ctrl), 0xF, 0xF, false))

// permlane{32,16}_swap: cross-row lane exchange on the VALU pipe (gfx950).
// v_permlane32_swap_b32: rows2-3(a) <-> rows0-1(b). a=b=x => r.x = x_lo||x_lo, r.y = x_hi||x_hi.
//   partner(lane<32) = x_hi[lane] = r.y ; partner(lane>=32) = x_lo[lane-32] = r.x.
// v_permlane16_swap_b32: odd rows(a) <-> even rows(b). a=b=x => r.x = [r0,r0,r2,r2], r.y = [r1,r1,r3,r3].
//   partner(lane&16==0) = r.y ; partner(lane&16) = r.x.
typedef int v2i __attribute__((ext_vector_type(2)));
#if __has_builtin(__builtin_amdgcn_permlane32_swap)
__device__ __forceinline__ float xor32_pl(float x, bool hi) {
    v2i r = __builtin_amdgcn_permlane32_swap(__float_as_int(x), __float_as_int(x), false, false);
    return __int_as_float(hi ? r.x : r.y);
}
#else
__device__ __forceinline__ float xor32_pl(float x, bool hi) { return __shfl_xor(x, 32); }
#endif
#if __has_builtin(__builtin_amdgcn_permlane16_swap)
__device__ __forceinline__ float xor16_pl(float x, bool hi16) {
    v2i r = __builtin_amdgcn_permlane16_swap(__float_as_int(x), __float_as_int(x), false, false);
    return __int_as_float(hi16 ? r.x : r.y);
}
#else
__device__ __forceinline__ float xor16_pl(float x, bool hi16) { return __shfl_xor(x, 16); }
#endif

// precomputed per-launch tables
__device__ float2 g_tw512[256];     // exp(-i*pi*j/256)
__device__ float2 g_twu[512];       // exp(-i*pi*k/512)
__device__ int    g_fbs[128];       // first bin per mel (forced even)
__device__ int    g_fbc[128];       // bin count per mel (forced even, zero-padded)
__device__ float  g_fbw[MAXW][128]; // compact weights, transposed for coalescing

// -------- K0: twiddle tables + sparse filterbank compaction (128 blocks) --------
__global__ __launch_bounds__(256)
void pcen_setup_kernel(const float* __restrict__ fb)
{
    const int tid = threadIdx.x;
    const int m   = blockIdx.x;

    if (m == 0) {
        float s, c;
        __sincosf(-3.14159265358979323846f * (float)tid / 256.0f, &s, &c);
        g_tw512[tid] = make_float2(c, s);
    }
    if (m == 1) {
        for (int k = tid; k < 512; k += 256) {
            float s, c;
            __sincosf(-3.14159265358979323846f * (float)k / 512.0f, &s, &c);
            g_twu[k] = make_float2(c, s);
        }
    }

    __shared__ int smn[256], smx[256];
    int s = 0x7fffffff, e = -1;
    for (int f = tid; f < 513; f += 256) {
        if (fb[f * 128 + m] != 0.0f) { s = min(s, f); e = max(e, f); }
    }
    smn[tid] = s; smx[tid] = e;
    __syncthreads();
    for (int o = 128; o > 0; o >>= 1) {
        if (tid < o) {
            smn[tid] = min(smn[tid], smn[tid + o]);
            smx[tid] = max(smx[tid], smx[tid + o]);
        }
        __syncthreads();
    }
    int S   = (smx[0] < 0) ? 0 : (smn[0] & ~1);           // force even start
    int cnt = (smx[0] < 0) ? 0 : (smx[0] - S + 1);
    if (cnt > MAXW) cnt = MAXW;
    int cntE = (cnt + 1) & ~1;                             // force even count
    if (tid == 0) { g_fbs[m] = S; g_fbc[m] = cntE; }
    for (int k = tid; k < cntE; k += 256)
        g_fbw[k][m] = (k < cnt) ? fb[(S + k) * 128 + m] : 0.0f;
}

// -------- K1: frames -> windowed rFFT magnitude (f32) -> mel energies E[b][m][t] --------
// All 6 cross-lane FFT stages on the VALU pipe: 32/16 via permlane_swap, 8/4/2/1 via DPP.
__global__ __launch_bounds__(256)
void pcen_spec_kernel(const float* __restrict__ x, const float* __restrict__ win,
                      float* __restrict__ E)
{
    __shared__ float span[SPAN];        // 19.0 KB
    __shared__ float mags[FPB][MROW];   // 33.3 KB

    const int tid = threadIdx.x;
    const int t0  = blockIdx.x * FPB;
    const int b   = blockIdx.y;

    // ---- load input span with reflect padding ----
    const float* xb = x + (size_t)b * SRLEN;
    for (int j = tid; j < SPAN; j += 256) {
        int src = t0 * 256 + j - 512;
        src = (src < 0) ? -src : src;
        src = (src >= SRLEN) ? (2 * SRLEN - 2 - src) : src;
        span[j] = xb[src];
    }
    __syncthreads();

    const int lane = tid & 63;
    const int wid  = tid >> 6;
    const int lp   = rev6(lane);
    const int p0lane = rev6((64 - lp) & 63);

    // each wave handles 4 frames, fully in registers
    for (int ff = 0; ff < 4; ++ff) {
        const int fr = wid * 4 + ff;
        float zre[8], zim[8];

        // pack: n = rg*64 + lane ; z[n] = xw[2n] + i*xw[2n+1]
        #pragma unroll
        for (int rg = 0; rg < 8; ++rg) {
            int n = rg * 64 + lane;
            float2 sp = *(const float2*)&span[fr * 256 + 2 * n];
            float2 w  = *(const float2*)&win[2 * n];
            zre[rg] = sp.x * w.x;
            zim[rg] = sp.y * w.y;
        }

        // ---- DIF stage m=256: pairs (r, r+4) ----
        #pragma unroll
        for (int rg = 0; rg < 4; ++rg) {
            const float2 tw = g_tw512[rg * 64 + lane];
            float ar = zre[rg], ai = zim[rg], br = zre[rg + 4], bi = zim[rg + 4];
            zre[rg] = ar + br; zim[rg] = ai + bi;
            float dr = ar - br, di = ai - bi;
            zre[rg + 4] = dr * tw.x - di * tw.y;
            zim[rg + 4] = dr * tw.y + di * tw.x;
        }
        // ---- stage m=128: pairs (r, r+2) in each half ----
        #pragma unroll
        for (int h = 0; h < 2; ++h) {
            #pragma unroll
            for (int q = 0; q < 2; ++q) {
                int rt = h * 4 + q, rb = rt + 2;
                const float2 tw = g_tw512[(q * 64 + lane) * 2];
                float ar = zre[rt], ai = zim[rt], br = zre[rb], bi = zim[rb];
                zre[rt] = ar + br; zim[rt] = ai + bi;
                float dr = ar - br, di = ai - bi;
                zre[rb] = dr * tw.x - di * tw.y;
                zim[rb] = dr * tw.y + di * tw.x;
            }
        }
        // ---- stage m=64: pairs (r, r+1) ----
        {
            const float2 tw = g_tw512[lane * 4];
            #pragma unroll
            for (int rt = 0; rt < 8; rt += 2) {
                int rb = rt + 1;
                float ar = zre[rt], ai = zim[rt], br = zre[rb], bi = zim[rb];
                zre[rt] = ar + br; zim[rt] = ai + bi;
                float dr = ar - br, di = ai - bi;
                zre[rb] = dr * tw.x - di * tw.y;
                zim[rb] = dr * tw.y + di * tw.x;
            }
        }

        // ---- 6 cross-lane stages, all on the VALU pipe ----
        #define BFLY(MASK, PRE, PIM) { \
            const float2 tw = g_tw512[(lane & ((MASK) - 1)) * (256 / (MASK))]; \
            const bool bot = (lane & (MASK)) != 0; \
            const float cw = bot ? tw.x : 1.0f; \
            const float sw = bot ? tw.y : 0.0f; \
            const float sg = bot ? -1.0f : 1.0f; \
            _Pragma("unroll") \
            for (int rg = 0; rg < 8; ++rg) { \
                float orr = zre[rg], oii = zim[rg]; \
                float prr = (PRE); \
                float pri = (PIM); \
                float tr = fmaf(sg, orr, prr); \
                float ti = fmaf(sg, oii, pri); \
                zre[rg] = tr * cw - ti * sw; \
                zim[rg] = tr * sw + ti * cw; \
            } }

        BFLY(32, xor32_pl(orr, bot), xor32_pl(oii, bot))
        BFLY(16, xor16_pl(orr, bot), xor16_pl(oii, bot))
        BFLY(8,  DPPF(DPPF(orr, 0x140), 0x141), DPPF(DPPF(oii, 0x140), 0x141))  // xor8 = 15^7
        BFLY(4,  DPPF(DPPF(orr, 0x141), 0x1B),  DPPF(DPPF(oii, 0x141), 0x1B))   // xor4 = 7^3
        BFLY(2,  DPPF(orr, 0x4E),               DPPF(oii, 0x4E))                // xor2
        BFLY(1,  DPPF(orr, 0xB1),               DPPF(oii, 0xB1))                // xor1
        #undef BFLY

        // natural Z order: lane lp holds Z[8*lp + q] at reg R3[q]; R3 = {0,4,2,6,1,5,3,7}
        #define WRE(q) zre[(q)==0?0:(q)==1?4:(q)==2?2:(q)==3?6:(q)==4?1:(q)==5?5:(q)==6?3:7]
        #define WIM(q) zim[(q)==0?0:(q)==1?4:(q)==2?2:(q)==3?6:(q)==4?1:(q)==5?5:(q)==6?3:7]

        float mg[8];
        #define MAG(q, MR, MI) { \
            float zr = WRE(q), zi = WIM(q); \
            float mr = (MR), mi = (MI); \
            const float2 tw = g_twu[lp * 8 + (q)]; \
            float xer = 0.5f * (zr + mr), xei = 0.5f * (zi - mi); \
            float xo  = 0.5f * (zi + mi), xoi = 0.5f * (mr - zr); \
            float xr = xer + tw.x * xo - tw.y * xoi; \
            float xi = xei + tw.x * xoi + tw.y * xo; \
            mg[q] = sqrtf(xr * xr + xi * xi); }

        {
            float p0re = __shfl(WRE(0), p0lane);
            float p0im = __shfl(WIM(0), p0lane);
            MAG(0, p0re, p0im)
        }
        {
            float pr = __shfl_xor(WRE(4), 63);
            float pi = __shfl_xor(WIM(4), 63);
            MAG(4, pr, pi)
        }
        #pragma unroll
        for (int q = 1; q <= 3; ++q) {
            float prq  = __shfl_xor(WRE(q), 63);
            float piq  = __shfl_xor(WIM(q), 63);
            float prq8 = __shfl_xor(WRE(8 - q), 63);
            float piq8 = __shfl_xor(WIM(8 - q), 63);
            MAG(q, prq8, piq8)
            MAG(8 - q, prq, piq)
        }
        #undef MAG
        #undef WRE
        #undef WIM

        *(float4*)&mags[fr][lp * 8]     = make_float4(mg[0], mg[1], mg[2], mg[3]);
        *(float4*)&mags[fr][lp * 8 + 4] = make_float4(mg[4], mg[5], mg[6], mg[7]);
        if (lane == 0) {
            mags[fr][512] = fabsf(zre[0] - zim[0]);  // Nyquist
            mags[fr][513] = 0.0f;                    // pad for float2 mel reads
        }
    }
    __syncthreads();

    // ---- sparse mel projection via float2: m = tid&127, fg = tid>>7 covers 8 frames ----
    const int m  = tid & 127;
    const int fg = tid >> 7;
    const int s0 = g_fbs[m];   // even
    const int cn = g_fbc[m];   // even
    float acc[8] = {0, 0, 0, 0, 0, 0, 0, 0};
    for (int k = 0; k < cn; k += 2) {
        const float w0 = g_fbw[k][m];
        const float w1 = g_fbw[k + 1][m];
        const int f = s0 + k;
        #pragma unroll
        for (int j = 0; j < 8; ++j) {
            const float2 v = *(const float2*)&mags[fg * 8 + j][f];
            acc[j] = fmaf(w0, v.x, fmaf(w1, v.y, acc[j]));
        }
    }
    #pragma unroll
    for (int j = 0; j < 8; ++j) {
        int t = t0 + fg * 8 + j;
        if (t < NFRAMES)
            E[((size_t)(b * 128 + m)) * NFRAMES + t] = acc[j];
    }
}

// -------- K2: per-(b,m) IIR scan + PCEN nonlinearity (global access, scan-only LDS,
//          r==0.5 sqrt fast path) --------
__global__ __launch_bounds__(256)
void pcen_scan_kernel(float* __restrict__ E, const float* __restrict__ alpha,
                      const float* __restrict__ delta, const float* __restrict__ rr)
{
    __shared__ float sA[256], sB[256];
    const int tid = threadIdx.x;
    const int bm  = blockIdx.x;
    const int m   = bm & 127;
    const size_t row = (size_t)bm * NFRAMES;

    const float al = alpha[m], de = delta[m], rp = rr[m];
    const bool  half_pow = (rp == 0.5f);
    const float dpr = half_pow ? sqrtf(de) : __powf(de, rp);

    float e[10];
    #pragma unroll
    for (int j = 0; j < 10; ++j) {
        int t = tid * 10 + j;
        e[j] = (t < NFRAMES) ? E[row + t] : 0.0f;
    }

    // local fold of (a,b) pairs; identity (1,0) for padding
    float A = 1.0f, B = 0.0f;
    #pragma unroll
    for (int j = 0; j < 10; ++j) {
        int t = tid * 10 + j;
        bool v = t < NFRAMES;
        float a  = (t == 0) ? 1.0f : (v ? 0.96f : 1.0f);
        float bv = (t == 0) ? e[0] : (v ? 0.04f * e[j] : 0.0f);
        A *= a;
        B = a * B + bv;
    }
    sA[tid] = A; sB[tid] = B;
    __syncthreads();

    // Hillis-Steele inclusive scan over thread chunks
    for (int off = 1; off < 256; off <<= 1) {
        float a2 = sA[tid], b2 = sB[tid];
        float a1 = 1.0f, b1 = 0.0f;
        if (tid >= off) { a1 = sA[tid - off]; b1 = sB[tid - off]; }
        __syncthreads();
        sA[tid] = a1 * a2;
        sB[tid] = a2 * b1 + b2;
        __syncthreads();
    }
    float M = (tid > 0) ? sB[tid - 1] : 0.0f;   // carry: M before this chunk

    #pragma unroll
    for (int j = 0; j < 10; ++j) {
        int t = tid * 10 + j;
        bool v = t < NFRAMES;
        float a  = (t == 0) ? 1.0f : (v ? 0.96f : 1.0f);
        float bv = (t == 0) ? e[0] : (v ? 0.04f * e[j] : 0.0f);
        M = a * M + bv;
        if (v) {
            float inv = __powf(M + 1e-6f, -al);            // smooth^-1
            float val = fmaf(e[j], inv, de);
            float pw  = half_pow ? sqrtf(val) : __powf(val, rp);
            E[row + t] = pw - dpr;
        }
    }
}

extern "C" void kernel_launch(void* const* d_in, const int* in_sizes, int n_in,
                              void* d_out, int out_size, void* d_ws, size_t ws_size,
                              hipStream_t stream)
{
    const float* x     = (const float*)d_in[0];
    const float* alpha = (const float*)d_in[1];
    const float* delta = (const float*)d_in[2];
    const float* r     = (const float*)d_in[3];
    const float* fb    = (const float*)d_in[4];
    const float* win   = (const float*)d_in[5];
    float* out = (float*)d_out;

    pcen_setup_kernel<<<128, 256, 0, stream>>>(fb);
    dim3 g1((NFRAMES + FPB - 1) / FPB, 32);   // 157 x 32
    pcen_spec_kernel<<<g1, 256, 0, stream>>>(x, win, out);
    pcen_scan_kernel<<<32 * 128, 256, 0, stream>>>(out, alpha, delta, r);
}